// Round 2
// baseline (734.151 us; speedup 1.0000x reference)
//
#include <hip/hip_runtime.h>
#include <math.h>

// ProbAttention (Informer ProbSparse) — B=8 L=2048 H=8 D=64 u=40
// q/k/v reshape(B,H,L,D) is a flat reinterpretation -> treat as (BH=64, L, D) contiguous.
#define LSEQ 2048
#define DDIM 64
#define UU   40
#define NBH  64
#define NCHUNK 8
#define CROWS  256            // rows per k-chunk (CROWS*NCHUNK == LSEQ)
#define CTX_ELEMS (NBH*UU*DDIM)   // 163840

// ---------------- K0: bin sample indices by 256-row chunk (shared across all bh) ----
// One wave per l. Stable wave-parallel bucket sort via ballot/popcount.
// sidx[l][0..39] = indices grouped by chunk; soff[l][c] = (base<<8)|count.
__global__ __launch_bounds__(256) void k0_sort(
    const int* __restrict__ idxs, int* __restrict__ sidx, int* __restrict__ soff) {
  int l = blockIdx.x * 4 + (threadIdx.x >> 6);
  int lane = threadIdx.x & 63;
  int v = 0, c = NCHUNK;              // lanes >= UU get invalid chunk
  if (lane < UU) { v = idxs[l * UU + lane]; c = v >> 8; }
  unsigned long long lower = (1ull << lane) - 1ull;   // low `lane` bits
  int base = 0;
#pragma unroll
  for (int cc = 0; cc < NCHUNK; ++cc) {
    unsigned long long m = __ballot(c == cc);
    if (c == cc) {
      int rank = __popcll(m & lower);
      sidx[l * UU + base + rank] = v;
    }
    int cnt = __popcll(m);
    if (lane == cc) soff[l * NCHUNK + cc] = (base << 8) | cnt;
    base += cnt;
  }
}

// ---------------- K12 v3: gather through LDS-resident k chunk ----------------
// 512 blocks: bh = b&63, chunk = b>>6. Stage k[bh, c*256 .. +256) (64KB) once —
// k is read from HBM exactly once, coalesced. Each wave owns one l per iteration:
// 8 slots x 8 lanes process up to 8 samples of that l in parallel; gathered rows
// come from LDS (69 TB/s) instead of the random-gather L2-fill path that capped
// v2 at ~28 B/cyc/CU. Partial (max,sum) per (bh,chunk,l) -> Mpart (lives in the
// attn output region, overwritten later by k45).
// b%8 == bh%8 -> all 8 chunk-blocks of a bh share an XCD; their lock-step l-sweep
// keeps the 8x-reused q rows hot in that XCD's L2.
__global__ __launch_bounds__(256, 2) void k12_gather(
    const float* __restrict__ q, const float* __restrict__ k,
    const int* __restrict__ sidx, const int* __restrict__ soff,
    float2* __restrict__ Mpart) {
  __shared__ float kt[CROWS * DDIM];   // 64KB
  int b = blockIdx.x;
  int bh = b & 63;
  int c  = b >> 6;
  int t  = threadIdx.x;

  const float4* src = (const float4*)(k + ((size_t)bh * LSEQ + c * CROWS) * DDIM);
  float4* dst = (float4*)kt;
#pragma unroll
  for (int i = 0; i < 16; ++i) dst[t + 256 * i] = src[t + 256 * i];
  __syncthreads();

  int w = t >> 6, lane = t & 63;
  int slot = lane >> 3, sub = lane & 7;

  for (int l = w; l < LSEQ; l += 4) {
    int oc   = soff[l * NCHUNK + c];        // wave-uniform broadcast load
    int cnt  = oc & 255;
    int base = oc >> 8;
    const float4* qr = (const float4*)(q + ((size_t)bh * LSEQ + l) * DDIM);
    float4 qa = qr[sub];        // bytes [0,128) of q row — one line, broadcast x8
    float4 qb = qr[sub + 8];    // bytes [128,256)
    float mx = -INFINITY, sm = 0.f;
    for (int it = 0; it < cnt; it += 8) {
      int sj = it + slot;                    // slot-uniform across 8 lanes
      float d = 0.f;
      if (sj < cnt) {
        int row = sidx[l * UU + base + sj] & (CROWS - 1);
        const float4* kr = (const float4*)(kt + row * DDIM);
        float4 a = kr[sub], bb = kr[sub + 8];
        d = qa.x * a.x + qa.y * a.y + qa.z * a.z + qa.w * a.w
          + qb.x * bb.x + qb.y * bb.y + qb.z * bb.z + qb.w * bb.w;
      }
      // intra-slot dot reduce (xor 1,2,4 stays inside the 8-lane slot)
      d += __shfl_xor(d, 1, 64);
      d += __shfl_xor(d, 2, 64);
      d += __shfl_xor(d, 4, 64);
      float dm = (sj < cnt) ? d : -INFINITY;
      float ds = (sj < cnt) ? d : 0.f;
      // cross-slot reduce (xor 8,16,32)
      dm = fmaxf(dm, __shfl_xor(dm, 8, 64));
      dm = fmaxf(dm, __shfl_xor(dm, 16, 64));
      dm = fmaxf(dm, __shfl_xor(dm, 32, 64));
      ds += __shfl_xor(ds, 8, 64);
      ds += __shfl_xor(ds, 16, 64);
      ds += __shfl_xor(ds, 32, 64);
      mx = fmaxf(mx, dm);
      sm += ds;
    }
    if (lane == 0) Mpart[((size_t)bh * NCHUNK + c) * LSEQ + l] = make_float2(mx, sm);
  }
}

// ---------------- K3: top-40 per head; combines Mpart chunks during load -----------
// desc value, tie -> smaller index (matches jax.lax.top_k stability)
__global__ __launch_bounds__(256) void k3_topk(const float2* __restrict__ Mp,
                                               int* __restrict__ Mtop) {
  int bh = blockIdx.x;
  int t = threadIdx.x;
  int w = t >> 6;
  int lane = t & 63;
  float v[8];
#pragma unroll
  for (int j = 0; j < 8; ++j) {
    int l = t + 256 * j;
    float mxv = -INFINITY, smv = 0.f;
#pragma unroll
    for (int c = 0; c < NCHUNK; ++c) {
      float2 p = Mp[((size_t)bh * NCHUNK + c) * LSEQ + l];
      mxv = fmaxf(mxv, p.x);
      smv += p.y;
    }
    v[j] = mxv - smv * (1.0f / (float)LSEQ);
  }
  __shared__ float swv[4];
  __shared__ int   swi[4];
  __shared__ int   win;
  for (int it = 0; it < UU; ++it) {
    float bv = -INFINITY; int bi = 0x7fffffff;
#pragma unroll
    for (int j = 0; j < 8; ++j) {
      if (v[j] > bv) { bv = v[j]; bi = t + 256 * j; }
    }
#pragma unroll
    for (int off = 32; off > 0; off >>= 1) {
      float ov = __shfl_xor(bv, off, 64);
      int   oi = __shfl_xor(bi, off, 64);
      if (ov > bv || (ov == bv && oi < bi)) { bv = ov; bi = oi; }
    }
    if (lane == 0) { swv[w] = bv; swi[w] = bi; }
    __syncthreads();
    if (t == 0) {
      float fv = swv[0]; int fi = swi[0];
#pragma unroll
      for (int j = 1; j < 4; ++j) {
        if (swv[j] > fv || (swv[j] == fv && swi[j] < fi)) { fv = swv[j]; fi = swi[j]; }
      }
      Mtop[bh * UU + it] = fi;
      win = fi;
    }
    __syncthreads();
    int wi = win;
#pragma unroll
    for (int j = 0; j < 8; ++j)
      if (wi == t + 256 * j) v[j] = -INFINITY;   // static index, predicated
  }
}

// ---------------- K45: fused scores + softmax -> normalized attn ----------------
// (reverted to round-0 4-lane geometry: 2 shfls/dot, 32 iters — the 8-lane variant
// tripled shfl count and regressed ~20us)
// 640 blocks: bh = b&63, ug = b>>6 (4 u each). 32KB LDS -> 4 blocks/CU capacity.
// Softmax: wave w owns row u=w (full 2048 in LDS, pure shfl reduce).
// Also zeroes ctx (640*256 == CTX_ELEMS exactly) for k7's atomics.
__global__ __launch_bounds__(256, 4) void k45_scores_softmax(
    const float* __restrict__ q, const float* __restrict__ k,
    const int* __restrict__ Mtop, float* __restrict__ attn,
    float* __restrict__ ctx) {
  __shared__ float sct[4 * LSEQ];    // 32KB, [u][l]
  int b = blockIdx.x;
  int bh = b & 63;
  int u0 = (b >> 6) * 4;
  int t = threadIdx.x;
  int g = t >> 2;
  int sub = t & 3;

  ctx[b * 256 + t] = 0.f;

  float4 qv[4][4];
#pragma unroll
  for (int u = 0; u < 4; ++u) {
    int qi = Mtop[bh * UU + u0 + u];
    const float4* qr = (const float4*)(q + (size_t)(bh * LSEQ + qi) * DDIM);
#pragma unroll
    for (int m = 0; m < 4; ++m) qv[u][m] = qr[4 * m + sub];
  }

  const float* kb = k + (size_t)bh * LSEQ * DDIM;
#pragma unroll 1
  for (int p = 0; p < 32; ++p) {
    int l = p * 64 + g;
    const float4* kr = (const float4*)(kb + (size_t)l * DDIM);
    float4 ks[4];
#pragma unroll
    for (int m = 0; m < 4; ++m) ks[m] = kr[4 * m + sub];
    float d[4];
#pragma unroll
    for (int u = 0; u < 4; ++u) {
      float s = 0.f;
#pragma unroll
      for (int m = 0; m < 4; ++m) {
        float4 x = qv[u][m], a = ks[m];
        s += x.x * a.x + x.y * a.y + x.z * a.z + x.w * a.w;
      }
      s += __shfl_xor(s, 1, 64);
      s += __shfl_xor(s, 2, 64);
      d[u] = s * 0.125f;
    }
    if (sub == 0) {
#pragma unroll
      for (int u = 0; u < 4; ++u) sct[u * LSEQ + l] = d[u];
    }
  }
  __syncthreads();

  // softmax: wave w owns row w
  int w = t >> 6, lane = t & 63;
  float* row = sct + w * LSEQ;
  float vv[32];
  float mx = -INFINITY;
#pragma unroll
  for (int j = 0; j < 32; ++j) { vv[j] = row[lane + 64 * j]; mx = fmaxf(mx, vv[j]); }
#pragma unroll
  for (int off = 32; off > 0; off >>= 1) mx = fmaxf(mx, __shfl_xor(mx, off, 64));
  float sm = 0.f;
#pragma unroll
  for (int j = 0; j < 32; ++j) { vv[j] = __expf(vv[j] - mx); sm += vv[j]; }
#pragma unroll
  for (int off = 32; off > 0; off >>= 1) sm += __shfl_xor(sm, off, 64);
  float inv = 1.0f / sm;
  float* ap = attn + (size_t)(bh * UU + u0 + w) * LSEQ;
#pragma unroll
  for (int j = 0; j < 32; ++j) ap[lane + 64 * j] = vv[j] * inv;
}

// ---------------- K7: context[bh,u,d] += sum_l attn[bh,u,l] * v[bh,l,d] ----------------
// 512 blocks: bh = b&63, l-eighth = b>>6 (256 l). v tile staged in 64KB LDS once;
// wave w owns u-group w*10..w*10+10 (attn rows read once per block, broadcast loads).
// fp32 atomicAdd into ctx (zeroed by k45).
__global__ __launch_bounds__(256) void k7_context(
    const float* __restrict__ attn, const float* __restrict__ v,
    float* __restrict__ ctx) {
  __shared__ float vt[256 * DDIM];   // 64KB
  int b = blockIdx.x;
  int bh = b & 63;
  int l0 = (b >> 6) * 256;
  int t = threadIdx.x;

  const float4* src = (const float4*)(v + ((size_t)bh * LSEQ + l0) * DDIM);
  float4* dst = (float4*)vt;
#pragma unroll
  for (int i = 0; i < 16; ++i) dst[t + 256 * i] = src[t + 256 * i];
  __syncthreads();

  int w = t >> 6;
  int d = t & 63;
  const float* ab = attn + ((size_t)bh * UU + w * 10) * LSEQ + l0;
  float acc[10];
#pragma unroll
  for (int u = 0; u < 10; ++u) acc[u] = 0.f;
#pragma unroll 1
  for (int l4 = 0; l4 < 64; ++l4) {
    int l = l4 * 4;
    float4 av[10];
#pragma unroll
    for (int u = 0; u < 10; ++u)
      av[u] = *(const float4*)(ab + (size_t)u * LSEQ + l);   // 64 lanes same addr -> broadcast
#pragma unroll
    for (int i = 0; i < 4; ++i) {
      float vvv = vt[(l + i) * DDIM + d];
#pragma unroll
      for (int u = 0; u < 10; ++u)
        acc[u] = fmaf(((const float*)&av[u])[i], vvv, acc[u]);
    }
  }
#pragma unroll
  for (int u = 0; u < 10; ++u)
    atomicAdd(&ctx[((size_t)bh * UU + w * 10 + u) * DDIM + d], acc[u]);
}

extern "C" void kernel_launch(void* const* d_in, const int* in_sizes, int n_in,
                              void* d_out, int out_size, void* d_ws, size_t ws_size,
                              hipStream_t stream) {
  const float* q   = (const float*)d_in[0];
  const float* k   = (const float*)d_in[1];
  const float* v   = (const float*)d_in[2];
  const int*   idx = (const int*)d_in[3];

  float* ctx  = (float*)d_out;                  // [NBH, UU, DDIM]
  float* attn = (float*)d_out + CTX_ELEMS;      // [NBH, UU, LSEQ]
  // Mpart scratch lives in the attn output region until k45 overwrites it:
  // needs NBH*NCHUNK*LSEQ float2 = 2.1M floats < 5.24M available.
  float2* Mpart = (float2*)attn;

  int* sidx = (int*)d_ws;                        // LSEQ*UU    = 81920 ints
  int* soff = sidx + LSEQ * UU;                  // LSEQ*8     = 16384 ints
  int* Mtop = soff + LSEQ * NCHUNK;              // NBH*UU     = 2560 ints

  k0_sort<<<LSEQ / 4, 256, 0, stream>>>(idx, sidx, soff);
  k12_gather<<<NBH * NCHUNK, 256, 0, stream>>>(q, k, sidx, soff, Mpart);
  k3_topk<<<NBH, 256, 0, stream>>>(Mpart, Mtop);
  k45_scores_softmax<<<NBH * 10, 256, 0, stream>>>(q, k, Mtop, attn, ctx);
  k7_context<<<NBH * 8, 256, 0, stream>>>(attn, v, ctx);
}

// Round 3
// 399.564 us; speedup vs baseline: 1.8374x; 1.8374x over previous
//
#include <hip/hip_runtime.h>
#include <math.h>

// ProbAttention (Informer ProbSparse) — B=8 L=2048 H=8 D=64 u=40
// q/k/v reshape(B,H,L,D) is a flat reinterpretation -> treat as (BH=64, L, D) contiguous.
#define LSEQ 2048
#define DDIM 64
#define UU   40
#define NBH  64
#define CTX_ELEMS (NBH*UU*DDIM)   // 163840

typedef float f32x4 __attribute__((ext_vector_type(4)));

// ---------------- K12 v4: round-1 8-lane geometry + NON-TEMPORAL gathered loads ----
// 4096 blocks: bh = b&63, ltile = b>>6 (32 l per block). Thread = (g = t>>3, sub = t&7).
// Gather is the measured wall: 1.34GB of random 256B k-rows through L2 at ~17 TB/s
// effective (half the streaming ceiling). A/B this round: nt loads on k rows bypass
// L1 allocation — if the wall is the L1/TCP miss path, this relieves it; if it's
// L2-side random-row BW, no change (and only dedup/byte-reduction can help).
__global__ __launch_bounds__(256, 4) void k12_sample_m(
    const float* __restrict__ q, const float* __restrict__ k,
    const int* __restrict__ idxs, float* __restrict__ M) {
  int b = blockIdx.x;
  int bh = b & 63;
  int ltile = b >> 6;
  int t = threadIdx.x;
  int g = t >> 3;
  int sub = t & 7;
  int l = ltile * 32 + g;

  const float4* qr = (const float4*)(q + (size_t)(bh * LSEQ + l) * DDIM);
  float4 qa = qr[sub];       // floats [sub*4 .. sub*4+4)       (line 0 of row)
  float4 qb = qr[sub + 8];   // floats [32+sub*4 .. 32+sub*4+4) (line 1 of row)

  const float* kbase = k + (size_t)bh * LSEQ * DDIM;
  const int4* ir = (const int4*)(idxs + l * UU);

  float mx = -INFINITY, sm = 0.f;
#pragma unroll 1
  for (int s4 = 0; s4 < UU / 4; ++s4) {
    int4 jv = ir[s4];
    const f32x4* k0 = (const f32x4*)(kbase + (size_t)jv.x * DDIM);
    const f32x4* k1 = (const f32x4*)(kbase + (size_t)jv.y * DDIM);
    const f32x4* k2 = (const f32x4*)(kbase + (size_t)jv.z * DDIM);
    const f32x4* k3 = (const f32x4*)(kbase + (size_t)jv.w * DDIM);
    f32x4 a0 = __builtin_nontemporal_load(k0 + sub);
    f32x4 b0 = __builtin_nontemporal_load(k0 + sub + 8);
    f32x4 a1 = __builtin_nontemporal_load(k1 + sub);
    f32x4 b1 = __builtin_nontemporal_load(k1 + sub + 8);
    f32x4 a2 = __builtin_nontemporal_load(k2 + sub);
    f32x4 b2 = __builtin_nontemporal_load(k2 + sub + 8);
    f32x4 a3 = __builtin_nontemporal_load(k3 + sub);
    f32x4 b3 = __builtin_nontemporal_load(k3 + sub + 8);
    float d0 = qa.x * a0.x + qa.y * a0.y + qa.z * a0.z + qa.w * a0.w
             + qb.x * b0.x + qb.y * b0.y + qb.z * b0.z + qb.w * b0.w;
    float d1 = qa.x * a1.x + qa.y * a1.y + qa.z * a1.z + qa.w * a1.w
             + qb.x * b1.x + qb.y * b1.y + qb.z * b1.z + qb.w * b1.w;
    float d2 = qa.x * a2.x + qa.y * a2.y + qa.z * a2.z + qa.w * a2.w
             + qb.x * b2.x + qb.y * b2.y + qb.z * b2.z + qb.w * b2.w;
    float d3 = qa.x * a3.x + qa.y * a3.y + qa.z * a3.z + qa.w * a3.w
             + qb.x * b3.x + qb.y * b3.y + qb.z * b3.z + qb.w * b3.w;
    // 8-lane butterfly reduce (xor bits 0..2 stay inside the group)
    d0 += __shfl_xor(d0, 1, 64); d0 += __shfl_xor(d0, 2, 64); d0 += __shfl_xor(d0, 4, 64);
    d1 += __shfl_xor(d1, 1, 64); d1 += __shfl_xor(d1, 2, 64); d1 += __shfl_xor(d1, 4, 64);
    d2 += __shfl_xor(d2, 1, 64); d2 += __shfl_xor(d2, 2, 64); d2 += __shfl_xor(d2, 4, 64);
    d3 += __shfl_xor(d3, 1, 64); d3 += __shfl_xor(d3, 2, 64); d3 += __shfl_xor(d3, 4, 64);
    mx = fmaxf(fmaxf(fmaxf(mx, d0), fmaxf(d1, d2)), d3);
    sm += (d0 + d1) + (d2 + d3);   // same accumulation order as passing baseline
  }
  if (sub == 0) M[bh * LSEQ + l] = mx - sm * (1.0f / (float)LSEQ);
}

// ---------------- K3: top-40 per head; M in regs, shfl + LDS reduce ----------------
// desc value, tie -> smaller index (matches jax.lax.top_k stability)
__global__ __launch_bounds__(256) void k3_topk(const float* __restrict__ M,
                                               int* __restrict__ Mtop) {
  int bh = blockIdx.x;
  int t = threadIdx.x;
  int w = t >> 6;
  int lane = t & 63;
  float v[8];
#pragma unroll
  for (int j = 0; j < 8; ++j) v[j] = M[bh * LSEQ + t + 256 * j];
  __shared__ float swv[4];
  __shared__ int   swi[4];
  __shared__ int   win;
  for (int it = 0; it < UU; ++it) {
    float bv = -INFINITY; int bi = 0x7fffffff;
#pragma unroll
    for (int j = 0; j < 8; ++j) {
      if (v[j] > bv) { bv = v[j]; bi = t + 256 * j; }
    }
#pragma unroll
    for (int off = 32; off > 0; off >>= 1) {
      float ov = __shfl_xor(bv, off, 64);
      int   oi = __shfl_xor(bi, off, 64);
      if (ov > bv || (ov == bv && oi < bi)) { bv = ov; bi = oi; }
    }
    if (lane == 0) { swv[w] = bv; swi[w] = bi; }
    __syncthreads();
    if (t == 0) {
      float fv = swv[0]; int fi = swi[0];
#pragma unroll
      for (int j = 1; j < 4; ++j) {
        if (swv[j] > fv || (swv[j] == fv && swi[j] < fi)) { fv = swv[j]; fi = swi[j]; }
      }
      Mtop[bh * UU + it] = fi;
      win = fi;
    }
    __syncthreads();
    int wi = win;
#pragma unroll
    for (int j = 0; j < 8; ++j)
      if (wi == t + 256 * j) v[j] = -INFINITY;   // static index, predicated
  }
}

// ---------------- K45: fused scores + softmax -> normalized attn ----------------
// Round-0 geometry (4-lane, 2 shfl/dot, 32 iters — its best measured form).
// 640 blocks: bh = b&63, ug = b>>6 (4 u each). 32KB LDS -> 4 blocks/CU capacity.
// Softmax: wave w owns row u=w (full 2048 in LDS, pure shfl reduce).
// Also zeroes ctx (640*256 == CTX_ELEMS exactly) for k7's atomics.
__global__ __launch_bounds__(256, 4) void k45_scores_softmax(
    const float* __restrict__ q, const float* __restrict__ k,
    const int* __restrict__ Mtop, float* __restrict__ attn,
    float* __restrict__ ctx) {
  __shared__ float sct[4 * LSEQ];    // 32KB, [u][l]
  int b = blockIdx.x;
  int bh = b & 63;
  int u0 = (b >> 6) * 4;
  int t = threadIdx.x;
  int g = t >> 2;
  int sub = t & 3;

  ctx[b * 256 + t] = 0.f;

  float4 qv[4][4];
#pragma unroll
  for (int u = 0; u < 4; ++u) {
    int qi = Mtop[bh * UU + u0 + u];
    const float4* qr = (const float4*)(q + (size_t)(bh * LSEQ + qi) * DDIM);
#pragma unroll
    for (int m = 0; m < 4; ++m) qv[u][m] = qr[4 * m + sub];
  }

  const float* kb = k + (size_t)bh * LSEQ * DDIM;
#pragma unroll 1
  for (int p = 0; p < 32; ++p) {
    int l = p * 64 + g;
    const float4* kr = (const float4*)(kb + (size_t)l * DDIM);
    float4 ks[4];
#pragma unroll
    for (int m = 0; m < 4; ++m) ks[m] = kr[4 * m + sub];
    float d[4];
#pragma unroll
    for (int u = 0; u < 4; ++u) {
      float s = 0.f;
#pragma unroll
      for (int m = 0; m < 4; ++m) {
        float4 x = qv[u][m], a = ks[m];
        s += x.x * a.x + x.y * a.y + x.z * a.z + x.w * a.w;
      }
      s += __shfl_xor(s, 1, 64);
      s += __shfl_xor(s, 2, 64);
      d[u] = s * 0.125f;
    }
    if (sub == 0) {
#pragma unroll
      for (int u = 0; u < 4; ++u) sct[u * LSEQ + l] = d[u];
    }
  }
  __syncthreads();

  // softmax: wave w owns row w
  int w = t >> 6, lane = t & 63;
  float* row = sct + w * LSEQ;
  float vv[32];
  float mx = -INFINITY;
#pragma unroll
  for (int j = 0; j < 32; ++j) { vv[j] = row[lane + 64 * j]; mx = fmaxf(mx, vv[j]); }
#pragma unroll
  for (int off = 32; off > 0; off >>= 1) mx = fmaxf(mx, __shfl_xor(mx, off, 64));
  float sm = 0.f;
#pragma unroll
  for (int j = 0; j < 32; ++j) { vv[j] = __expf(vv[j] - mx); sm += vv[j]; }
#pragma unroll
  for (int off = 32; off > 0; off >>= 1) sm += __shfl_xor(sm, off, 64);
  float inv = 1.0f / sm;
  float* ap = attn + (size_t)(bh * UU + u0 + w) * LSEQ;
#pragma unroll
  for (int j = 0; j < 32; ++j) ap[lane + 64 * j] = vv[j] * inv;
}

// ---------------- K7: context[bh,u,d] += sum_l attn[bh,u,l] * v[bh,l,d] ----------------
// 512 blocks: bh = b&63, l-eighth = b>>6 (256 l). v tile staged in 64KB LDS once;
// wave w owns u-group w*10..w*10+10 (attn rows read once per block, broadcast loads).
// fp32 atomicAdd into ctx (zeroed by k45).
__global__ __launch_bounds__(256) void k7_context(
    const float* __restrict__ attn, const float* __restrict__ v,
    float* __restrict__ ctx) {
  __shared__ float vt[256 * DDIM];   // 64KB
  int b = blockIdx.x;
  int bh = b & 63;
  int l0 = (b >> 6) * 256;
  int t = threadIdx.x;

  const float4* src = (const float4*)(v + ((size_t)bh * LSEQ + l0) * DDIM);
  float4* dst = (float4*)vt;
#pragma unroll
  for (int i = 0; i < 16; ++i) dst[t + 256 * i] = src[t + 256 * i];
  __syncthreads();

  int w = t >> 6;
  int d = t & 63;
  const float* ab = attn + ((size_t)bh * UU + w * 10) * LSEQ + l0;
  float acc[10];
#pragma unroll
  for (int u = 0; u < 10; ++u) acc[u] = 0.f;
#pragma unroll 1
  for (int l4 = 0; l4 < 64; ++l4) {
    int l = l4 * 4;
    float4 av[10];
#pragma unroll
    for (int u = 0; u < 10; ++u)
      av[u] = *(const float4*)(ab + (size_t)u * LSEQ + l);   // 64 lanes same addr -> broadcast
#pragma unroll
    for (int i = 0; i < 4; ++i) {
      float vvv = vt[(l + i) * DDIM + d];
#pragma unroll
      for (int u = 0; u < 10; ++u)
        acc[u] = fmaf(((const float*)&av[u])[i], vvv, acc[u]);
    }
  }
#pragma unroll
  for (int u = 0; u < 10; ++u)
    atomicAdd(&ctx[((size_t)bh * UU + w * 10 + u) * DDIM + d], acc[u]);
}

extern "C" void kernel_launch(void* const* d_in, const int* in_sizes, int n_in,
                              void* d_out, int out_size, void* d_ws, size_t ws_size,
                              hipStream_t stream) {
  const float* q   = (const float*)d_in[0];
  const float* k   = (const float*)d_in[1];
  const float* v   = (const float*)d_in[2];
  const int*   idx = (const int*)d_in[3];

  float* ctx  = (float*)d_out;                  // [NBH, UU, DDIM]
  float* attn = (float*)d_out + CTX_ELEMS;      // [NBH, UU, LSEQ]

  float* M    = (float*)d_ws;                                    // 131072 f
  int*   Mtop = (int*)(M + NBH * LSEQ);                          // 2560 i

  k12_sample_m<<<NBH * 64, 256, 0, stream>>>(q, k, idx, M);
  k3_topk<<<NBH, 256, 0, stream>>>(M, Mtop);
  k45_scores_softmax<<<NBH * 10, 256, 0, stream>>>(q, k, Mtop, attn, ctx);
  k7_context<<<NBH * 8, 256, 0, stream>>>(attn, v, ctx);
}

// Round 4
// 301.397 us; speedup vs baseline: 2.4358x; 1.3257x over previous
//
#include <hip/hip_runtime.h>
#include <math.h>

// ProbAttention (Informer ProbSparse) — B=8 L=2048 H=8 D=64 u=40
// q/k/v reshape(B,H,L,D) is a flat reinterpretation -> treat as (BH=64, L, D) contiguous.
#define LSEQ 2048
#define DDIM 64
#define UU   40
#define NBH  64
#define NCHUNK 8
#define CROWS  256            // rows per k-chunk (CROWS*NCHUNK == LSEQ)
#define CTX_ELEMS (NBH*UU*DDIM)   // 163840

// 8-lane-group sum via DPP (pure VALU — keeps the LDS pipe free for k-row reads).
// quad_perm[1,0,3,2]=xor1, quad_perm[2,3,0,1]=xor2, ROW_HALF_MIRROR=xor-within-8.
// All three patterns stay inside an 8-lane group (quads and half-rows never cross it).
__device__ __forceinline__ float grp8_sum(float x) {
  float t;
  t = __int_as_float(__builtin_amdgcn_update_dpp(0, __float_as_int(x), 0xB1, 0xF, 0xF, false));
  x += t;
  t = __int_as_float(__builtin_amdgcn_update_dpp(0, __float_as_int(x), 0x4E, 0xF, 0xF, false));
  x += t;
  t = __int_as_float(__builtin_amdgcn_update_dpp(0, __float_as_int(x), 0x141, 0xF, 0xF, false));
  x += t;
  return x;
}

// ---------------- K0: bin sample indices by 256-row chunk (shared across all bh) ----
// One wave per l. Stable wave-parallel bucket sort via ballot/popcount. [proven R2]
__global__ __launch_bounds__(256) void k0_sort(
    const int* __restrict__ idxs, int* __restrict__ sidx, int* __restrict__ soff) {
  int l = blockIdx.x * 4 + (threadIdx.x >> 6);
  int lane = threadIdx.x & 63;
  int v = 0, c = NCHUNK;              // lanes >= UU get invalid chunk
  if (lane < UU) { v = idxs[l * UU + lane]; c = v >> 8; }
  unsigned long long lower = (1ull << lane) - 1ull;
  int base = 0;
#pragma unroll
  for (int cc = 0; cc < NCHUNK; ++cc) {
    unsigned long long m = __ballot(c == cc);
    if (c == cc) {
      int rank = __popcll(m & lower);
      sidx[l * UU + base + rank] = v;
    }
    int cnt = __popcll(m);
    if (lane == cc) soff[l * NCHUNK + cc] = (base << 8) | cnt;
    base += cnt;
  }
}

// ---------------- K12 v7: LDS-chunk gather, wide-parallel, DPP-reduced -------------
// 512 blocks (bh = b&63, c = b>>6), 512 threads (8 waves), 64KB LDS, 2 blocks/CU.
// k read from HBM exactly ONCE (32MB total vs round-1's 1.34GB through the random
// 256B-row L2 fill path measured at 17 TB/s — the confirmed wall).
// Wave = 8 groups x 8 lanes; each group owns one l per batch (8 l's in flight).
// Per batch: q row (2 coalesced float4/lane), sidx rows prefetched to regs (MLP 8),
// then per sample: 2 swizzled ds_read_b128 + 16 FMA + 3 DPP adds (no ds-pipe shfls).
// Partials (max,sum) per (bh,c,l) -> Mpart in attn region [proven R2]; k3 combines.
// XCD note: blocks of one bh all map to XCD bh%8 -> q[bh] re-reads stay L2-local.
__global__ __launch_bounds__(512, 4) void k12_gather(
    const float* __restrict__ q, const float* __restrict__ k,
    const int* __restrict__ sidx, const int* __restrict__ soff,
    float2* __restrict__ Mpart) {
  __shared__ float4 kt[CROWS * 16];   // 64KB, row-swizzled: slot = col ^ (row&7)
  int b = blockIdx.x;
  int bh = b & 63;
  int c  = b >> 6;
  int t  = threadIdx.x;

  // stage k chunk, swizzled; reads coalesced (lane-consecutive float4)
  {
    const float4* src = (const float4*)(k + ((size_t)bh * LSEQ + c * CROWS) * DDIM);
#pragma unroll
    for (int j = 0; j < 8; ++j) {
      int i = t + 512 * j;            // float4 index in chunk
      int row = i >> 4, col = i & 15;
      kt[row * 16 + (col ^ (row & 7))] = src[i];
    }
  }
  __syncthreads();

  int w = t >> 6;            // wave 0..7 owns l in [w*256, w*256+256)
  int lane = t & 63;
  int g = lane >> 3;         // group 0..7 (one l each per batch)
  int sub = lane & 7;

  for (int lb = 0; lb < 256; lb += 8) {
    int l = w * 256 + lb + g;
    const float4* qr = (const float4*)(q + ((size_t)bh * LSEQ + l) * DDIM);
    float4 qa = qr[sub];        // q row bytes [0,128)
    float4 qb = qr[sub + 8];    // q row bytes [128,256)
    int oc   = soff[l * NCHUNK + c];
    int cnt  = oc & 255;
    int base = oc >> 8;
    // prefetch up to 8 sample rows into regs (static unroll -> stays in VGPRs, MLP 8)
    int rowv[8];
#pragma unroll
    for (int s = 0; s < 8; ++s) {
      int ix = base + s; ix = ix < UU ? ix : UU - 1;   // clamp keeps reads in this l's row
      rowv[s] = sidx[l * UU + ix] & (CROWS - 1);
    }
    float mx = -INFINITY, sm = 0.f;
#pragma unroll
    for (int s = 0; s < 8; ++s) {
      if (s < cnt) {
        int row = rowv[s];
        int sl = (sub ^ (row & 7));
        float4 a  = kt[row * 16 + sl];        // col sub   (de-swizzle)
        float4 bq = kt[row * 16 + 8 + sl];    // col sub+8
        float d = qa.x * a.x + qa.y * a.y + qa.z * a.z + qa.w * a.w
                + qb.x * bq.x + qb.y * bq.y + qb.z * bq.z + qb.w * bq.w;
        d = grp8_sum(d);
        mx = fmaxf(mx, d);
        sm += d;
      }
    }
    for (int s = 8; s < cnt; ++s) {           // rare residual (P(cnt>8) ~ 5%)
      int row = sidx[l * UU + base + s] & (CROWS - 1);
      int sl = (sub ^ (row & 7));
      float4 a  = kt[row * 16 + sl];
      float4 bq = kt[row * 16 + 8 + sl];
      float d = qa.x * a.x + qa.y * a.y + qa.z * a.z + qa.w * a.w
              + qb.x * bq.x + qb.y * bq.y + qb.z * bq.z + qb.w * bq.w;
      d = grp8_sum(d);
      mx = fmaxf(mx, d);
      sm += d;
    }
    if (sub == 0) Mpart[((size_t)bh * NCHUNK + c) * LSEQ + l] = make_float2(mx, sm);
  }
}

// ---------------- K3: top-40 per head; combines Mpart chunks during load [proven R2]
// desc value, tie -> smaller index (matches jax.lax.top_k stability)
__global__ __launch_bounds__(256) void k3_topk(const float2* __restrict__ Mp,
                                               int* __restrict__ Mtop) {
  int bh = blockIdx.x;
  int t = threadIdx.x;
  int w = t >> 6;
  int lane = t & 63;
  float v[8];
#pragma unroll
  for (int j = 0; j < 8; ++j) {
    int l = t + 256 * j;
    float mxv = -INFINITY, smv = 0.f;
#pragma unroll
    for (int c = 0; c < NCHUNK; ++c) {
      float2 p = Mp[((size_t)bh * NCHUNK + c) * LSEQ + l];
      mxv = fmaxf(mxv, p.x);
      smv += p.y;
    }
    v[j] = mxv - smv * (1.0f / (float)LSEQ);
  }
  __shared__ float swv[4];
  __shared__ int   swi[4];
  __shared__ int   win;
  for (int it = 0; it < UU; ++it) {
    float bv = -INFINITY; int bi = 0x7fffffff;
#pragma unroll
    for (int j = 0; j < 8; ++j) {
      if (v[j] > bv) { bv = v[j]; bi = t + 256 * j; }
    }
#pragma unroll
    for (int off = 32; off > 0; off >>= 1) {
      float ov = __shfl_xor(bv, off, 64);
      int   oi = __shfl_xor(bi, off, 64);
      if (ov > bv || (ov == bv && oi < bi)) { bv = ov; bi = oi; }
    }
    if (lane == 0) { swv[w] = bv; swi[w] = bi; }
    __syncthreads();
    if (t == 0) {
      float fv = swv[0]; int fi = swi[0];
#pragma unroll
      for (int j = 1; j < 4; ++j) {
        if (swv[j] > fv || (swv[j] == fv && swi[j] < fi)) { fv = swv[j]; fi = swi[j]; }
      }
      Mtop[bh * UU + it] = fi;
      win = fi;
    }
    __syncthreads();
    int wi = win;
#pragma unroll
    for (int j = 0; j < 8; ++j)
      if (wi == t + 256 * j) v[j] = -INFINITY;   // static index, predicated
  }
}

// ---------------- K45: fused scores + softmax -> normalized attn [round-0 proven] --
// 640 blocks: bh = b&63, ug = b>>6 (4 u each). 32KB LDS -> 4 blocks/CU capacity.
// Softmax: wave w owns row u=w (full 2048 in LDS, pure shfl reduce).
// Also zeroes ctx (640*256 == CTX_ELEMS exactly) for k7's atomics.
__global__ __launch_bounds__(256, 4) void k45_scores_softmax(
    const float* __restrict__ q, const float* __restrict__ k,
    const int* __restrict__ Mtop, float* __restrict__ attn,
    float* __restrict__ ctx) {
  __shared__ float sct[4 * LSEQ];    // 32KB, [u][l]
  int b = blockIdx.x;
  int bh = b & 63;
  int u0 = (b >> 6) * 4;
  int t = threadIdx.x;
  int g = t >> 2;
  int sub = t & 3;

  ctx[b * 256 + t] = 0.f;

  float4 qv[4][4];
#pragma unroll
  for (int u = 0; u < 4; ++u) {
    int qi = Mtop[bh * UU + u0 + u];
    const float4* qr = (const float4*)(q + (size_t)(bh * LSEQ + qi) * DDIM);
#pragma unroll
    for (int m = 0; m < 4; ++m) qv[u][m] = qr[4 * m + sub];
  }

  const float* kb = k + (size_t)bh * LSEQ * DDIM;
#pragma unroll 1
  for (int p = 0; p < 32; ++p) {
    int l = p * 64 + g;
    const float4* kr = (const float4*)(kb + (size_t)l * DDIM);
    float4 ks[4];
#pragma unroll
    for (int m = 0; m < 4; ++m) ks[m] = kr[4 * m + sub];
    float d[4];
#pragma unroll
    for (int u = 0; u < 4; ++u) {
      float s = 0.f;
#pragma unroll
      for (int m = 0; m < 4; ++m) {
        float4 x = qv[u][m], a = ks[m];
        s += x.x * a.x + x.y * a.y + x.z * a.z + x.w * a.w;
      }
      s += __shfl_xor(s, 1, 64);
      s += __shfl_xor(s, 2, 64);
      d[u] = s * 0.125f;
    }
    if (sub == 0) {
#pragma unroll
      for (int u = 0; u < 4; ++u) sct[u * LSEQ + l] = d[u];
    }
  }
  __syncthreads();

  // softmax: wave w owns row w
  int w = t >> 6, lane = t & 63;
  float* row = sct + w * LSEQ;
  float vv[32];
  float mx = -INFINITY;
#pragma unroll
  for (int j = 0; j < 32; ++j) { vv[j] = row[lane + 64 * j]; mx = fmaxf(mx, vv[j]); }
#pragma unroll
  for (int off = 32; off > 0; off >>= 1) mx = fmaxf(mx, __shfl_xor(mx, off, 64));
  float sm = 0.f;
#pragma unroll
  for (int j = 0; j < 32; ++j) { vv[j] = __expf(vv[j] - mx); sm += vv[j]; }
#pragma unroll
  for (int off = 32; off > 0; off >>= 1) sm += __shfl_xor(sm, off, 64);
  float inv = 1.0f / sm;
  float* ap = attn + (size_t)(bh * UU + u0 + w) * LSEQ;
#pragma unroll
  for (int j = 0; j < 32; ++j) ap[lane + 64 * j] = vv[j] * inv;
}

// ---------------- K7: context[bh,u,d] += sum_l attn[bh,u,l] * v[bh,l,d] [proven] ----
// 512 blocks: bh = b&63, l-eighth = b>>6 (256 l). v tile staged in 64KB LDS once;
// wave w owns u-group w*10..w*10+10 (attn rows read once per block, broadcast loads).
// fp32 atomicAdd into ctx (zeroed by k45).
__global__ __launch_bounds__(256) void k7_context(
    const float* __restrict__ attn, const float* __restrict__ v,
    float* __restrict__ ctx) {
  __shared__ float vt[256 * DDIM];   // 64KB
  int b = blockIdx.x;
  int bh = b & 63;
  int l0 = (b >> 6) * 256;
  int t = threadIdx.x;

  const float4* src = (const float4*)(v + ((size_t)bh * LSEQ + l0) * DDIM);
  float4* dst = (float4*)vt;
#pragma unroll
  for (int i = 0; i < 16; ++i) dst[t + 256 * i] = src[t + 256 * i];
  __syncthreads();

  int w = t >> 6;
  int d = t & 63;
  const float* ab = attn + ((size_t)bh * UU + w * 10) * LSEQ + l0;
  float acc[10];
#pragma unroll
  for (int u = 0; u < 10; ++u) acc[u] = 0.f;
#pragma unroll 1
  for (int l4 = 0; l4 < 64; ++l4) {
    int l = l4 * 4;
    float4 av[10];
#pragma unroll
    for (int u = 0; u < 10; ++u)
      av[u] = *(const float4*)(ab + (size_t)u * LSEQ + l);   // 64 lanes same addr -> broadcast
#pragma unroll
    for (int i = 0; i < 4; ++i) {
      float vvv = vt[(l + i) * DDIM + d];
#pragma unroll
      for (int u = 0; u < 10; ++u)
        acc[u] = fmaf(((const float*)&av[u])[i], vvv, acc[u]);
    }
  }
#pragma unroll
  for (int u = 0; u < 10; ++u)
    atomicAdd(&ctx[((size_t)bh * UU + w * 10 + u) * DDIM + d], acc[u]);
}

extern "C" void kernel_launch(void* const* d_in, const int* in_sizes, int n_in,
                              void* d_out, int out_size, void* d_ws, size_t ws_size,
                              hipStream_t stream) {
  const float* q   = (const float*)d_in[0];
  const float* k   = (const float*)d_in[1];
  const float* v   = (const float*)d_in[2];
  const int*   idx = (const int*)d_in[3];

  float* ctx  = (float*)d_out;                  // [NBH, UU, DDIM]
  float* attn = (float*)d_out + CTX_ELEMS;      // [NBH, UU, LSEQ]
  // Mpart scratch lives in the attn output region until k45 overwrites it:
  // NBH*NCHUNK*LSEQ float2 = 2.1M floats < 5.24M available. [proven R2]
  float2* Mpart = (float2*)attn;

  int* sidx = (int*)d_ws;                        // LSEQ*UU     = 81920 ints
  int* soff = sidx + LSEQ * UU;                  // LSEQ*NCHUNK = 16384 ints
  int* Mtop = soff + LSEQ * NCHUNK;              // NBH*UU      = 2560 ints

  k0_sort<<<LSEQ / 4, 256, 0, stream>>>(idx, sidx, soff);
  k12_gather<<<NBH * NCHUNK, 512, 0, stream>>>(q, k, sidx, soff, Mpart);
  k3_topk<<<NBH, 256, 0, stream>>>(Mpart, Mtop);
  k45_scores_softmax<<<NBH * 10, 256, 0, stream>>>(q, k, Mtop, attn, ctx);
  k7_context<<<NBH * 8, 256, 0, stream>>>(attn, v, ctx);
}

// Round 5
// 290.550 us; speedup vs baseline: 2.5268x; 1.0373x over previous
//
#include <hip/hip_runtime.h>
#include <math.h>

// ProbAttention (Informer ProbSparse) — B=8 L=2048 H=8 D=64 u=40
// q/k/v reshape(B,H,L,D) is a flat reinterpretation -> treat as (BH=64, L, D) contiguous.
#define LSEQ 2048
#define DDIM 64
#define UU   40
#define NBH  64
#define NCHUNK 8
#define CROWS  256            // rows per k-chunk (CROWS*NCHUNK == LSEQ)
#define CTX_ELEMS (NBH*UU*DDIM)   // 163840

// 8-lane-group sum via DPP (pure VALU — keeps the LDS pipe free for k-row reads).
__device__ __forceinline__ float grp8_sum(float x) {
  float t;
  t = __int_as_float(__builtin_amdgcn_update_dpp(0, __float_as_int(x), 0xB1, 0xF, 0xF, false));
  x += t;
  t = __int_as_float(__builtin_amdgcn_update_dpp(0, __float_as_int(x), 0x4E, 0xF, 0xF, false));
  x += t;
  t = __int_as_float(__builtin_amdgcn_update_dpp(0, __float_as_int(x), 0x141, 0xF, 0xF, false));
  x += t;
  return x;
}

// ---------------- K0: bin sample indices by 256-row chunk (shared across all bh) ----
__global__ __launch_bounds__(256) void k0_sort(
    const int* __restrict__ idxs, int* __restrict__ sidx, int* __restrict__ soff) {
  int l = blockIdx.x * 4 + (threadIdx.x >> 6);
  int lane = threadIdx.x & 63;
  int v = 0, c = NCHUNK;              // lanes >= UU get invalid chunk
  if (lane < UU) { v = idxs[l * UU + lane]; c = v >> 8; }
  unsigned long long lower = (1ull << lane) - 1ull;
  int base = 0;
#pragma unroll
  for (int cc = 0; cc < NCHUNK; ++cc) {
    unsigned long long m = __ballot(c == cc);
    if (c == cc) {
      int rank = __popcll(m & lower);
      sidx[l * UU + base + rank] = v;
    }
    int cnt = __popcll(m);
    if (lane == cc) soff[l * NCHUNK + cc] = (base << 8) | cnt;
    base += cnt;
  }
}

// ---------------- K12 v7: LDS-chunk gather (unchanged from R4, 83us measured) ------
// FETCH dropped 76->34MB as designed; now LDS-pipe-bound (2.1M b128 + 7.8M conflict
// cycles + predication waste). Left as-is this round; k45+k7 fusion is the bigger lever.
__global__ __launch_bounds__(512, 4) void k12_gather(
    const float* __restrict__ q, const float* __restrict__ k,
    const int* __restrict__ sidx, const int* __restrict__ soff,
    float2* __restrict__ Mpart) {
  __shared__ float4 kt[CROWS * 16];   // 64KB, row-swizzled: slot = col ^ (row&7)
  int b = blockIdx.x;
  int bh = b & 63;
  int c  = b >> 6;
  int t  = threadIdx.x;

  {
    const float4* src = (const float4*)(k + ((size_t)bh * LSEQ + c * CROWS) * DDIM);
#pragma unroll
    for (int j = 0; j < 8; ++j) {
      int i = t + 512 * j;            // float4 index in chunk
      int row = i >> 4, col = i & 15;
      kt[row * 16 + (col ^ (row & 7))] = src[i];
    }
  }
  __syncthreads();

  int w = t >> 6;            // wave 0..7 owns l in [w*256, w*256+256)
  int lane = t & 63;
  int g = lane >> 3;         // group 0..7 (one l each per batch)
  int sub = lane & 7;

  for (int lb = 0; lb < 256; lb += 8) {
    int l = w * 256 + lb + g;
    const float4* qr = (const float4*)(q + ((size_t)bh * LSEQ + l) * DDIM);
    float4 qa = qr[sub];
    float4 qb = qr[sub + 8];
    int oc   = soff[l * NCHUNK + c];
    int cnt  = oc & 255;
    int base = oc >> 8;
    int rowv[8];
#pragma unroll
    for (int s = 0; s < 8; ++s) {
      int ix = base + s; ix = ix < UU ? ix : UU - 1;
      rowv[s] = sidx[l * UU + ix] & (CROWS - 1);
    }
    float mx = -INFINITY, sm = 0.f;
#pragma unroll
    for (int s = 0; s < 8; ++s) {
      if (s < cnt) {
        int row = rowv[s];
        int sl = (sub ^ (row & 7));
        float4 a  = kt[row * 16 + sl];
        float4 bq = kt[row * 16 + 8 + sl];
        float d = qa.x * a.x + qa.y * a.y + qa.z * a.z + qa.w * a.w
                + qb.x * bq.x + qb.y * bq.y + qb.z * bq.z + qb.w * bq.w;
        d = grp8_sum(d);
        mx = fmaxf(mx, d);
        sm += d;
      }
    }
    for (int s = 8; s < cnt; ++s) {           // rare residual (P(cnt>8) ~ 5%)
      int row = sidx[l * UU + base + s] & (CROWS - 1);
      int sl = (sub ^ (row & 7));
      float4 a  = kt[row * 16 + sl];
      float4 bq = kt[row * 16 + 8 + sl];
      float d = qa.x * a.x + qa.y * a.y + qa.z * a.z + qa.w * a.w
              + qb.x * bq.x + qb.y * bq.y + qb.z * bq.z + qb.w * bq.w;
      d = grp8_sum(d);
      mx = fmaxf(mx, d);
      sm += d;
    }
    if (sub == 0) Mpart[((size_t)bh * NCHUNK + c) * LSEQ + l] = make_float2(mx, sm);
  }
}

// ---------------- K3: top-40 per head; combines Mpart chunks during load [proven] --
__global__ __launch_bounds__(256) void k3_topk(const float2* __restrict__ Mp,
                                               int* __restrict__ Mtop) {
  int bh = blockIdx.x;
  int t = threadIdx.x;
  int w = t >> 6;
  int lane = t & 63;
  float v[8];
#pragma unroll
  for (int j = 0; j < 8; ++j) {
    int l = t + 256 * j;
    float mxv = -INFINITY, smv = 0.f;
#pragma unroll
    for (int c = 0; c < NCHUNK; ++c) {
      float2 p = Mp[((size_t)bh * NCHUNK + c) * LSEQ + l];
      mxv = fmaxf(mxv, p.x);
      smv += p.y;
    }
    v[j] = mxv - smv * (1.0f / (float)LSEQ);
  }
  __shared__ float swv[4];
  __shared__ int   swi[4];
  __shared__ int   win;
  for (int it = 0; it < UU; ++it) {
    float bv = -INFINITY; int bi = 0x7fffffff;
#pragma unroll
    for (int j = 0; j < 8; ++j) {
      if (v[j] > bv) { bv = v[j]; bi = t + 256 * j; }
    }
#pragma unroll
    for (int off = 32; off > 0; off >>= 1) {
      float ov = __shfl_xor(bv, off, 64);
      int   oi = __shfl_xor(bi, off, 64);
      if (ov > bv || (ov == bv && oi < bi)) { bv = ov; bi = oi; }
    }
    if (lane == 0) { swv[w] = bv; swi[w] = bi; }
    __syncthreads();
    if (t == 0) {
      float fv = swv[0]; int fi = swi[0];
#pragma unroll
      for (int j = 1; j < 4; ++j) {
        if (swv[j] > fv || (swv[j] == fv && swi[j] < fi)) { fv = swv[j]; fi = swi[j]; }
      }
      Mtop[bh * UU + it] = fi;
      win = fi;
    }
    __syncthreads();
    int wi = win;
#pragma unroll
    for (int j = 0; j < 8; ++j)
      if (wi == t + 256 * j) v[j] = -INFINITY;   // static index, predicated
  }
}

// ---------------- K457: scores + softmax + CONTEXT, fully fused --------------------
// 640 blocks: bh = b&63, ug = b>>6 (4 u each). LDS = sct 32KB + vtile 16KB = 48KB
// -> 3 blocks/CU (need 2.5 avg). Phase A = proven R0 k45 geometry. Softmax writes
// normalized attn BOTH to global and back into sct. Phase B streams v in 64-row
// swizzled LDS tiles; each lane owns (d-quad dq, row-slice lq) and accumulates
// acc[4u]x(4d) in regs: per step 1 conflict-free b128 (row-swizzle: slot = dq^(r&3))
// + 4 broadcast b32 + 16 FMA — LDS-lean (the R2/R4 lesson). Partials reduce via
// 2 shfl_xor (lq) + 4KB LDS transpose (cross-wave). Kills k7 entirely: no attn
// re-read, NO atomics, no ctx zeroing, one less launch.
// v/q/k reads XCD-local: the 10 blocks of one bh all land on XCD b%8.
__global__ __launch_bounds__(256, 3) void k457_fused(
    const float* __restrict__ q, const float* __restrict__ k,
    const float* __restrict__ v, const int* __restrict__ Mtop,
    float* __restrict__ attn, float* __restrict__ ctx) {
  __shared__ float  sct[4 * LSEQ];     // 32KB, [u][l]: scores -> normalized attn
  __shared__ float4 vt4[64 * 16];      // 16KB v tile (swizzled); reused as pacc
  int b = blockIdx.x;
  int bh = b & 63;
  int u0 = (b >> 6) * 4;
  int t = threadIdx.x;

  // ---- phase A: scores (R0-proven 4-lane geometry) ----
  {
    int g = t >> 2;
    int sub = t & 3;
    float4 qv[4][4];
#pragma unroll
    for (int u = 0; u < 4; ++u) {
      int qi = Mtop[bh * UU + u0 + u];
      const float4* qr = (const float4*)(q + (size_t)(bh * LSEQ + qi) * DDIM);
#pragma unroll
      for (int m = 0; m < 4; ++m) qv[u][m] = qr[4 * m + sub];
    }
    const float* kb = k + (size_t)bh * LSEQ * DDIM;
#pragma unroll 1
    for (int p = 0; p < 32; ++p) {
      int l = p * 64 + g;
      const float4* kr = (const float4*)(kb + (size_t)l * DDIM);
      float4 ks[4];
#pragma unroll
      for (int m = 0; m < 4; ++m) ks[m] = kr[4 * m + sub];
      float d[4];
#pragma unroll
      for (int u = 0; u < 4; ++u) {
        float s = 0.f;
#pragma unroll
        for (int m = 0; m < 4; ++m) {
          float4 x = qv[u][m], a = ks[m];
          s += x.x * a.x + x.y * a.y + x.z * a.z + x.w * a.w;
        }
        s += __shfl_xor(s, 1, 64);
        s += __shfl_xor(s, 2, 64);
        d[u] = s * 0.125f;
      }
      if (sub == 0) {
#pragma unroll
        for (int u = 0; u < 4; ++u) sct[u * LSEQ + l] = d[u];
      }
    }
  }
  __syncthreads();

  // ---- softmax: wave w owns u-row w; write normalized to sct AND attn ----
  int w = t >> 6, lane = t & 63;
  {
    float* row = sct + w * LSEQ;
    float vv[32];
    float mx = -INFINITY;
#pragma unroll
    for (int j = 0; j < 32; ++j) { vv[j] = row[lane + 64 * j]; mx = fmaxf(mx, vv[j]); }
#pragma unroll
    for (int off = 32; off > 0; off >>= 1) mx = fmaxf(mx, __shfl_xor(mx, off, 64));
    float sm = 0.f;
#pragma unroll
    for (int j = 0; j < 32; ++j) { vv[j] = __expf(vv[j] - mx); sm += vv[j]; }
#pragma unroll
    for (int off = 32; off > 0; off >>= 1) sm += __shfl_xor(sm, off, 64);
    float inv = 1.0f / sm;
    float* ap = attn + (size_t)(bh * UU + u0 + w) * LSEQ;
#pragma unroll
    for (int j = 0; j < 32; ++j) {
      float a = vv[j] * inv;
      row[lane + 64 * j] = a;
      ap[lane + 64 * j] = a;
    }
  }
  __syncthreads();

  // ---- phase B: ctx[bh, u0+u, :] = sum_l attn[u][l] * v[bh, l, :] ----
  int dq = lane & 15;        // d-quad: d = dq*4 .. dq*4+3
  int lq = lane >> 4;        // row-slice 0..3
  float4 acc[4];
#pragma unroll
  for (int u = 0; u < 4; ++u) acc[u] = make_float4(0.f, 0.f, 0.f, 0.f);

  const float4* vsrc = (const float4*)(v + (size_t)bh * LSEQ * DDIM);
#pragma unroll 1
  for (int tile = 0; tile < 32; ++tile) {
    // stage 64 v rows, float4-slot swizzle: slot = c4 ^ (row&3)
#pragma unroll
    for (int i = 0; i < 4; ++i) {
      int idx = t + 256 * i;            // float4 index in tile (0..1023)
      int row = idx >> 4, c4 = idx & 15;
      vt4[row * 16 + (c4 ^ (row & 3))] = vsrc[tile * 1024 + idx];
    }
    __syncthreads();
#pragma unroll
    for (int i = 0; i < 4; ++i) {
      int r = w * 16 + i * 4 + lq;      // row in tile; wave w owns rows w*16..+16
      int l = tile * 64 + r;
      float4 vv4 = vt4[r * 16 + (dq ^ (r & 3))];   // 4 lq -> 4 distinct bank sets
#pragma unroll
      for (int u = 0; u < 4; ++u) {
        float a = sct[u * LSEQ + l];    // 4 distinct addrs/wave, 16-way broadcast
        acc[u].x += a * vv4.x;
        acc[u].y += a * vv4.y;
        acc[u].z += a * vv4.z;
        acc[u].w += a * vv4.w;
      }
    }
    __syncthreads();                    // protect vt4 before next stage
  }

  // reduce partials over lq (lane bits 4,5) — dq position preserved
#pragma unroll
  for (int u = 0; u < 4; ++u) {
    acc[u].x += __shfl_xor(acc[u].x, 16, 64);
    acc[u].y += __shfl_xor(acc[u].y, 16, 64);
    acc[u].z += __shfl_xor(acc[u].z, 16, 64);
    acc[u].w += __shfl_xor(acc[u].w, 16, 64);
    acc[u].x += __shfl_xor(acc[u].x, 32, 64);
    acc[u].y += __shfl_xor(acc[u].y, 32, 64);
    acc[u].z += __shfl_xor(acc[u].z, 32, 64);
    acc[u].w += __shfl_xor(acc[u].w, 32, 64);
  }
  __syncthreads();                      // vt4 free -> reuse as pacc[w][u][64]
  float* pacc = (float*)vt4;
  if (lq == 0) {
#pragma unroll
    for (int u = 0; u < 4; ++u)
      ((float4*)pacc)[(w * 4 + u) * 16 + dq] = acc[u];
  }
  __syncthreads();
  {
    int uu = t >> 6, d = t & 63;
    float s = pacc[(0 * 4 + uu) * 64 + d] + pacc[(1 * 4 + uu) * 64 + d]
            + pacc[(2 * 4 + uu) * 64 + d] + pacc[(3 * 4 + uu) * 64 + d];
    ctx[((size_t)bh * UU + u0 + uu) * DDIM + d] = s;
  }
}

extern "C" void kernel_launch(void* const* d_in, const int* in_sizes, int n_in,
                              void* d_out, int out_size, void* d_ws, size_t ws_size,
                              hipStream_t stream) {
  const float* q   = (const float*)d_in[0];
  const float* k   = (const float*)d_in[1];
  const float* v   = (const float*)d_in[2];
  const int*   idx = (const int*)d_in[3];

  float* ctx  = (float*)d_out;                  // [NBH, UU, DDIM]
  float* attn = (float*)d_out + CTX_ELEMS;      // [NBH, UU, LSEQ]
  // Mpart scratch lives in the attn output region; consumed by k3 BEFORE k457
  // overwrites the region with real attn. [proven R2/R4]
  float2* Mpart = (float2*)attn;

  int* sidx = (int*)d_ws;                        // LSEQ*UU     = 81920 ints
  int* soff = sidx + LSEQ * UU;                  // LSEQ*NCHUNK = 16384 ints
  int* Mtop = soff + LSEQ * NCHUNK;              // NBH*UU      = 2560 ints

  k0_sort<<<LSEQ / 4, 256, 0, stream>>>(idx, sidx, soff);
  k12_gather<<<NBH * NCHUNK, 512, 0, stream>>>(q, k, sidx, soff, Mpart);
  k3_topk<<<NBH, 256, 0, stream>>>(Mpart, Mtop);
  k457_fused<<<NBH * 10, 256, 0, stream>>>(q, k, v, Mtop, attn, ctx);
}